// Round 6
// baseline (385.735 us; speedup 1.0000x reference)
//
#include <hip/hip_runtime.h>
#include <math.h>

#define NN   100000
#define NE   1600000
#define FIN  256
#define HID  64
#define NC   40
#define NBKT 391          // buckets of 256 nodes: bucket = dst >> 8
#define EPB  6250         // edges per phase-A block (256 * 6250 = NE exactly)
#define CAP  4608         // per-bucket capacity (mean 4092, sd 64 -> 8 sigma slack)

typedef __attribute__((ext_vector_type(8))) short short8;
typedef __attribute__((ext_vector_type(4))) float float4v;

static __device__ __forceinline__ short f2bf(float f) {   // RNE f32 -> bf16 bits
    unsigned u = __float_as_uint(f);
    u += 0x7FFFu + ((u >> 16) & 1u);
    return (short)(u >> 16);
}
static __device__ __forceinline__ float bf2f(unsigned short b) {
    return __uint_as_float((unsigned)b << 16);
}

// ---------- W1 -> bf16, transposed to [n][k] ----------
__global__ __launch_bounds__(256) void w1cvt_k(const float* __restrict__ W1,
                                               short* __restrict__ w1t) {
    int t = blockIdx.x * 256 + threadIdx.x;   // 16384
    int k = t >> 6, n = t & 63;
    w1t[n * FIN + k] = f2bf(W1[k * HID + n]);
}

// ---------- phase A: partition edges into 391 coarse buckets ----------
__global__ __launch_bounds__(256) void phaseA_k(const int* __restrict__ src,
                                                const int* __restrict__ dst,
                                                const float* __restrict__ w,
                                                int* __restrict__ cursor,      // [NBKT*16]
                                                int2* __restrict__ bucketbuf) {
    __shared__ int  hist[NBKT];
    __shared__ int  sc[512];
    __shared__ int  loc_base[NBKT];
    __shared__ int  loc_cur[NBKT];
    __shared__ int  gb[NBKT];
    __shared__ int2 buf[EPB];          // 50 KB
    const int t  = threadIdx.x;
    const int e0 = blockIdx.x * EPB;

    for (int i = t; i < NBKT; i += 256) hist[i] = 0;
    __syncthreads();
    for (int i = t; i < EPB; i += 256) atomicAdd(&hist[dst[e0 + i] >> 8], 1);
    __syncthreads();
    sc[t]       = (t       < NBKT) ? hist[t]       : 0;
    sc[t + 256] = (t + 256 < NBKT) ? hist[t + 256] : 0;
    __syncthreads();
    for (int off = 1; off < 512; off <<= 1) {
        int a0 = (t >= off) ? sc[t - off] : 0;
        int a1 = sc[t + 256 - off];
        __syncthreads();
        sc[t] += a0; sc[t + 256] += a1;
        __syncthreads();
    }
    for (int i = t; i < NBKT; i += 256) {
        int base = sc[i] - hist[i];
        loc_base[i] = base;
        loc_cur[i]  = base;
        gb[i] = atomicAdd(&cursor[i * 16], hist[i]);
    }
    __syncthreads();
    for (int i = t; i < EPB; i += 256) {
        int e = e0 + i;
        int d = dst[e];
        int b = d >> 8;
        int p = atomicAdd(&loc_cur[b], 1);
        buf[p] = make_int2(src[e] | ((d & 255) << 17), __float_as_int(w[e]));
    }
    __syncthreads();
    for (int b = t; b < NBKT; b += 256) {
        int lb = loc_base[b], n = hist[b];
        int2* dstp = bucketbuf + (size_t)b * CAP + gb[b];
        for (int i = 0; i < n; ++i) dstp[i] = buf[lb + i];
    }
}

// ---------- scan of bucket counts -> bucket bases ----------
__global__ __launch_bounds__(512) void scanB_k(const int* __restrict__ cursor,
                                               int* __restrict__ bucketbase,
                                               int* __restrict__ row_start) {
    __shared__ int tmp[512];
    int t = threadIdx.x;
    int v = (t < NBKT) ? cursor[t * 16] : 0;
    tmp[t] = v;
    __syncthreads();
    for (int off = 1; off < 512; off <<= 1) {
        int add = (t >= off) ? tmp[t - off] : 0;
        __syncthreads(); tmp[t] += add; __syncthreads();
    }
    if (t < NBKT) bucketbase[t] = tmp[t] - v;
    if (t == 0) { bucketbase[NBKT] = NE; row_start[NN] = NE; }
}

// ---------- phase B: per-bucket CSR build + row_start + dinv ----------
__global__ __launch_bounds__(256) void phaseB_k(const int* __restrict__ bucketbase,
                                                const int2* __restrict__ bucketbuf,
                                                int2* __restrict__ e8,
                                                int* __restrict__ row_start,
                                                float* __restrict__ dinv) {
    __shared__ int2 buf[CAP];
    __shared__ int2 buf2[CAP];
    __shared__ int  hist2[256];
    __shared__ int  tmp[256];
    __shared__ int  base2[257];
    __shared__ int  cur2[256];
    const int b = blockIdx.x, t = threadIdx.x;
    const int g0   = bucketbase[b];
    const int cntb = bucketbase[b + 1] - g0;
    const int n0   = b * 256;
    const int nnb  = (NN - n0 < 256) ? (NN - n0) : 256;

    hist2[t] = 0;
    __syncthreads();
    const int2* bb = bucketbuf + (size_t)b * CAP;
    for (int i = t; i < cntb; i += 256) {
        int2 kv = bb[i];
        buf[i] = kv;
        atomicAdd(&hist2[kv.x >> 17], 1);
    }
    __syncthreads();
    int v = hist2[t];
    tmp[t] = v;
    __syncthreads();
    for (int off = 1; off < 256; off <<= 1) {
        int add = (t >= off) ? tmp[t - off] : 0;
        __syncthreads(); tmp[t] += add; __syncthreads();
    }
    int excl = tmp[t] - v;
    base2[t] = excl;
    cur2[t]  = excl;
    if (t == 0) base2[256] = cntb;
    if (t < nnb) row_start[n0 + t] = g0 + excl;
    __syncthreads();
    for (int i = t; i < cntb; i += 256) {
        int2 kv = buf[i];
        int d = kv.x >> 17;
        int p = atomicAdd(&cur2[d], 1);
        buf2[p] = make_int2(kv.x & 0x1FFFF, kv.y);
    }
    __syncthreads();
    for (int i = t; i < cntb; i += 256) e8[g0 + i] = buf2[i];
    if (t < nnb) {
        float s = 0.f;
        int j1 = base2[t + 1];
        for (int j = base2[t]; j < j1; ++j) s += __int_as_float(buf2[j].y);
        dinv[n0 + t] = rsqrtf(1.0f + s);
    }
}

// ---------- layer-1 GEMM via MFMA bf16, pre-scaled: h1'[r] = bf16(dinv[r] * (x@W1)[r]) ----------
// x staged to LDS via global_load_lds (16 async 1KB row-loads per wave, zero VGPR cost).
// LDS rows XOR-swizzled: byte ^= (row&7)<<4 (inverse-swizzled global source chunk, swizzled read).
// Each wave stages ONLY its own 16 rows -> no __syncthreads, one vmcnt(0) per wave.
__global__ __launch_bounds__(256) void gemm1_mfma_k(const float* __restrict__ x,
                                                    const short* __restrict__ w1t,  // bf16 [64][256]
                                                    const float* __restrict__ dinv,
                                                    unsigned short* __restrict__ h1) {
    __shared__ float xs[64 * 256];    // 64 KB: 64 rows x 1KB, swizzled
    const int wave = threadIdx.x >> 6;
    const int lane = threadIdx.x & 63;
    const int m    = lane & 15;
    const int quad = lane >> 4;
    const int r0   = blockIdx.x * 64 + wave * 16;

    float* ldsrow0 = xs + (wave * 16) * 256;
#pragma unroll
    for (int j = 0; j < 16; ++j) {
        int rr  = r0 + j;
        int rcl = (rr < NN) ? rr : (NN - 1);
        // source chunk index = lane ^ (row&7): inverse of the read-side swizzle
        const float* gsrc = x + (size_t)rcl * FIN + ((lane ^ (j & 7)) << 2);
        __builtin_amdgcn_global_load_lds(
            (const __attribute__((address_space(1))) void*)gsrc,
            (__attribute__((address_space(3))) void*)(ldsrow0 + j * 256),
            16, 0, 0);
    }
    asm volatile("s_waitcnt vmcnt(0)" ::: "memory");   // wave-private rows: no barrier needed

    const char* xrow = (const char*)(xs + (wave * 16 + m) * 256);
    const unsigned sw = (unsigned)(m & 7) << 4;        // byte XOR key

    float4v acc0 = {0.f,0.f,0.f,0.f}, acc1 = acc0, acc2 = acc0, acc3 = acc0;

#pragma unroll
    for (int kc = 0; kc < 8; ++kc) {
        const int kof = kc * 32 + quad * 8;
        const unsigned c0 = (unsigned)(kc * 128 + quad * 32);
        float4v xa = *(const float4v*)(xrow + (c0 ^ sw));
        float4v xb = *(const float4v*)(xrow + ((c0 + 16) ^ sw));
        short8 a;
        a[0] = f2bf(xa[0]); a[1] = f2bf(xa[1]); a[2] = f2bf(xa[2]); a[3] = f2bf(xa[3]);
        a[4] = f2bf(xb[0]); a[5] = f2bf(xb[1]); a[6] = f2bf(xb[2]); a[7] = f2bf(xb[3]);
        short8 b0 = *(const short8*)(w1t + (0 * 16 + m) * FIN + kof);
        short8 b1 = *(const short8*)(w1t + (1 * 16 + m) * FIN + kof);
        short8 b2 = *(const short8*)(w1t + (2 * 16 + m) * FIN + kof);
        short8 b3 = *(const short8*)(w1t + (3 * 16 + m) * FIN + kof);
        acc0 = __builtin_amdgcn_mfma_f32_16x16x32_bf16(a, b0, acc0, 0, 0, 0);
        acc1 = __builtin_amdgcn_mfma_f32_16x16x32_bf16(a, b1, acc1, 0, 0, 0);
        acc2 = __builtin_amdgcn_mfma_f32_16x16x32_bf16(a, b2, acc2, 0, 0, 0);
        acc3 = __builtin_amdgcn_mfma_f32_16x16x32_bf16(a, b3, acc3, 0, 0, 0);
    }
    // C/D layout: col = lane&15, row = quad*4 + reg
#pragma unroll
    for (int r = 0; r < 4; ++r) {
        int rr = r0 + quad * 4 + r;
        if (rr < NN) {
            float dv = dinv[rr];
            unsigned short* hp = h1 + (size_t)rr * HID + m;
            hp[0]  = (unsigned short)f2bf(acc0[r] * dv);
            hp[16] = (unsigned short)f2bf(acc1[r] * dv);
            hp[32] = (unsigned short)f2bf(acc2[r] * dv);
            hp[48] = (unsigned short)f2bf(acc3[r] * dv);
        }
    }
}

// ---------- gatherA: 8 edge-slots x 8 feat-lanes (uint4 = 8 bf16), 2-deep unroll ----------
// agg1 = dv*(sum w*h1'[s]) + dv*h1'[v]; emit R' = bf16(dv*relu(agg1+b1))
__global__ __launch_bounds__(256) void gatherA_k(const int* __restrict__ row_start,
                                                 const int2* __restrict__ e8,
                                                 const float* __restrict__ dinv,
                                                 const unsigned short* __restrict__ h,
                                                 const float* __restrict__ b1,
                                                 unsigned short* __restrict__ Rp) {
    const int v    = blockIdx.x * 4 + (threadIdx.x >> 6);
    const int lane = threadIdx.x & 63;
    const int slot = lane >> 3;          // edge slot 0..7
    const int fg   = lane & 7;           // feature group: 8 bf16 = 16 B
    const int i0 = row_start[v], i1 = row_start[v + 1];

    float acc[8] = {0.f,0.f,0.f,0.f,0.f,0.f,0.f,0.f};
    for (int i = i0; i < i1; i += 16) {   // 16 edges per iter -> 16 gathers in flight
        int iiA = i + slot, iiB = i + 8 + slot;
        bool okA = iiA < i1, okB = iiB < i1;
        int2 eA = e8[okA ? iiA : (NE - 1)];
        int2 eB = e8[okB ? iiB : (NE - 1)];
        int  sA = okA ? eA.x : 0;         // OOB slots gather hot row 0, weight 0
        int  sB = okB ? eB.x : 0;
        float wA = okA ? __int_as_float(eA.y) : 0.f;
        float wB = okB ? __int_as_float(eB.y) : 0.f;
        uint4 pA = *(const uint4*)(h + (size_t)sA * HID + fg * 8);
        uint4 pB = *(const uint4*)(h + (size_t)sB * HID + fg * 8);
        acc[0] = fmaf(__uint_as_float(pA.x << 16),         wA, acc[0]);
        acc[1] = fmaf(__uint_as_float(pA.x & 0xFFFF0000u), wA, acc[1]);
        acc[2] = fmaf(__uint_as_float(pA.y << 16),         wA, acc[2]);
        acc[3] = fmaf(__uint_as_float(pA.y & 0xFFFF0000u), wA, acc[3]);
        acc[4] = fmaf(__uint_as_float(pA.z << 16),         wA, acc[4]);
        acc[5] = fmaf(__uint_as_float(pA.z & 0xFFFF0000u), wA, acc[5]);
        acc[6] = fmaf(__uint_as_float(pA.w << 16),         wA, acc[6]);
        acc[7] = fmaf(__uint_as_float(pA.w & 0xFFFF0000u), wA, acc[7]);
        acc[0] = fmaf(__uint_as_float(pB.x << 16),         wB, acc[0]);
        acc[1] = fmaf(__uint_as_float(pB.x & 0xFFFF0000u), wB, acc[1]);
        acc[2] = fmaf(__uint_as_float(pB.y << 16),         wB, acc[2]);
        acc[3] = fmaf(__uint_as_float(pB.y & 0xFFFF0000u), wB, acc[3]);
        acc[4] = fmaf(__uint_as_float(pB.z << 16),         wB, acc[4]);
        acc[5] = fmaf(__uint_as_float(pB.z & 0xFFFF0000u), wB, acc[5]);
        acc[6] = fmaf(__uint_as_float(pB.w << 16),         wB, acc[6]);
        acc[7] = fmaf(__uint_as_float(pB.w & 0xFFFF0000u), wB, acc[7]);
    }
#pragma unroll
    for (int mk = 8; mk <= 32; mk <<= 1) {
#pragma unroll
        for (int q = 0; q < 8; ++q) acc[q] += __shfl_xor(acc[q], mk);
    }

    const float dv = dinv[v];
    uint4 ps = *(const uint4*)(h + (size_t)v * HID + fg * 8);   // self-loop row
    float4 bA = *(const float4*)(b1 + fg * 8);
    float4 bB = *(const float4*)(b1 + fg * 8 + 4);
    float r0 = fmaxf(dv * (acc[0] + __uint_as_float(ps.x << 16))         + bA.x, 0.f);
    float r1 = fmaxf(dv * (acc[1] + __uint_as_float(ps.x & 0xFFFF0000u)) + bA.y, 0.f);
    float r2 = fmaxf(dv * (acc[2] + __uint_as_float(ps.y << 16))         + bA.z, 0.f);
    float r3 = fmaxf(dv * (acc[3] + __uint_as_float(ps.y & 0xFFFF0000u)) + bA.w, 0.f);
    float r4 = fmaxf(dv * (acc[4] + __uint_as_float(ps.z << 16))         + bB.x, 0.f);
    float r5 = fmaxf(dv * (acc[5] + __uint_as_float(ps.z & 0xFFFF0000u)) + bB.y, 0.f);
    float r6 = fmaxf(dv * (acc[6] + __uint_as_float(ps.w << 16))         + bB.z, 0.f);
    float r7 = fmaxf(dv * (acc[7] + __uint_as_float(ps.w & 0xFFFF0000u)) + bB.w, 0.f);
    if (slot == 0) {
        uint4 pk;
        pk.x = (unsigned)(unsigned short)f2bf(dv * r0) | ((unsigned)(unsigned short)f2bf(dv * r1) << 16);
        pk.y = (unsigned)(unsigned short)f2bf(dv * r2) | ((unsigned)(unsigned short)f2bf(dv * r3) << 16);
        pk.z = (unsigned)(unsigned short)f2bf(dv * r4) | ((unsigned)(unsigned short)f2bf(dv * r5) << 16);
        pk.w = (unsigned)(unsigned short)f2bf(dv * r6) | ((unsigned)(unsigned short)f2bf(dv * r7) << 16);
        *(uint4*)(Rp + (size_t)v * HID + fg * 8) = pk;          // pre-scaled for gatherB
    }
}

// ---------- gatherB: same structure; agg2 = dv*(sum w*R'[s]) + dv*R'[v] ----------
__global__ __launch_bounds__(256) void gatherB_k(const int* __restrict__ row_start,
                                                 const int2* __restrict__ e8,
                                                 const float* __restrict__ dinv,
                                                 const unsigned short* __restrict__ Rp,
                                                 float* __restrict__ agg2) {
    const int v    = blockIdx.x * 4 + (threadIdx.x >> 6);
    const int lane = threadIdx.x & 63;
    const int slot = lane >> 3;
    const int fg   = lane & 7;
    const int i0 = row_start[v], i1 = row_start[v + 1];

    float acc[8] = {0.f,0.f,0.f,0.f,0.f,0.f,0.f,0.f};
    for (int i = i0; i < i1; i += 16) {
        int iiA = i + slot, iiB = i + 8 + slot;
        bool okA = iiA < i1, okB = iiB < i1;
        int2 eA = e8[okA ? iiA : (NE - 1)];
        int2 eB = e8[okB ? iiB : (NE - 1)];
        int  sA = okA ? eA.x : 0;
        int  sB = okB ? eB.x : 0;
        float wA = okA ? __int_as_float(eA.y) : 0.f;
        float wB = okB ? __int_as_float(eB.y) : 0.f;
        uint4 pA = *(const uint4*)(Rp + (size_t)sA * HID + fg * 8);
        uint4 pB = *(const uint4*)(Rp + (size_t)sB * HID + fg * 8);
        acc[0] = fmaf(__uint_as_float(pA.x << 16),         wA, acc[0]);
        acc[1] = fmaf(__uint_as_float(pA.x & 0xFFFF0000u), wA, acc[1]);
        acc[2] = fmaf(__uint_as_float(pA.y << 16),         wA, acc[2]);
        acc[3] = fmaf(__uint_as_float(pA.y & 0xFFFF0000u), wA, acc[3]);
        acc[4] = fmaf(__uint_as_float(pA.z << 16),         wA, acc[4]);
        acc[5] = fmaf(__uint_as_float(pA.z & 0xFFFF0000u), wA, acc[5]);
        acc[6] = fmaf(__uint_as_float(pA.w << 16),         wA, acc[6]);
        acc[7] = fmaf(__uint_as_float(pA.w & 0xFFFF0000u), wA, acc[7]);
        acc[0] = fmaf(__uint_as_float(pB.x << 16),         wB, acc[0]);
        acc[1] = fmaf(__uint_as_float(pB.x & 0xFFFF0000u), wB, acc[1]);
        acc[2] = fmaf(__uint_as_float(pB.y << 16),         wB, acc[2]);
        acc[3] = fmaf(__uint_as_float(pB.y & 0xFFFF0000u), wB, acc[3]);
        acc[4] = fmaf(__uint_as_float(pB.z << 16),         wB, acc[4]);
        acc[5] = fmaf(__uint_as_float(pB.z & 0xFFFF0000u), wB, acc[5]);
        acc[6] = fmaf(__uint_as_float(pB.w << 16),         wB, acc[6]);
        acc[7] = fmaf(__uint_as_float(pB.w & 0xFFFF0000u), wB, acc[7]);
    }
#pragma unroll
    for (int mk = 8; mk <= 32; mk <<= 1) {
#pragma unroll
        for (int q = 0; q < 8; ++q) acc[q] += __shfl_xor(acc[q], mk);
    }

    const float dv = dinv[v];
    uint4 ps = *(const uint4*)(Rp + (size_t)v * HID + fg * 8);
    if (slot == 0) {
        float4 oA, oB;
        oA.x = dv * (acc[0] + __uint_as_float(ps.x << 16));
        oA.y = dv * (acc[1] + __uint_as_float(ps.x & 0xFFFF0000u));
        oA.z = dv * (acc[2] + __uint_as_float(ps.y << 16));
        oA.w = dv * (acc[3] + __uint_as_float(ps.y & 0xFFFF0000u));
        oB.x = dv * (acc[4] + __uint_as_float(ps.z << 16));
        oB.y = dv * (acc[5] + __uint_as_float(ps.z & 0xFFFF0000u));
        oB.z = dv * (acc[6] + __uint_as_float(ps.w << 16));
        oB.w = dv * (acc[7] + __uint_as_float(ps.w & 0xFFFF0000u));
        *(float4*)(agg2 + (size_t)v * HID + fg * 8)     = oA;
        *(float4*)(agg2 + (size_t)v * HID + fg * 8 + 4) = oB;
    }
}

// ---------- gemm3 + log_softmax: out = logsm(agg2 @ W2 + b2), thread per node ----------
__global__ __launch_bounds__(256) void gemm3_logsm_k(const float* __restrict__ agg2,
                                                     const float* __restrict__ W2,
                                                     const float* __restrict__ b2,
                                                     float* __restrict__ out) {
    __shared__ float w2s[HID * NC];
    __shared__ float b2s[NC];
    for (int i = threadIdx.x; i < HID * NC; i += 256) w2s[i] = W2[i];
    if (threadIdx.x < NC) b2s[threadIdx.x] = b2[threadIdx.x];
    __syncthreads();

    const int r = blockIdx.x * 256 + threadIdx.x;
    if (r >= NN) return;
    float acc[NC];
#pragma unroll
    for (int c = 0; c < NC; ++c) acc[c] = b2s[c];

    const float4* row4 = (const float4*)(agg2 + (size_t)r * HID);
    for (int kk = 0; kk < HID; kk += 4) {
        float4 v = row4[kk >> 2];
#pragma unroll
        for (int c = 0; c < NC; ++c) {
            acc[c] = fmaf(v.x, w2s[(kk + 0) * NC + c], acc[c]);
            acc[c] = fmaf(v.y, w2s[(kk + 1) * NC + c], acc[c]);
            acc[c] = fmaf(v.z, w2s[(kk + 2) * NC + c], acc[c]);
            acc[c] = fmaf(v.w, w2s[(kk + 3) * NC + c], acc[c]);
        }
    }
    float m = acc[0];
#pragma unroll
    for (int c = 1; c < NC; ++c) m = fmaxf(m, acc[c]);
    float s = 0.f;
#pragma unroll
    for (int c = 0; c < NC; ++c) s += __expf(acc[c] - m);
    float lg = m + __logf(s);
    float* outp = out + (size_t)r * NC;
#pragma unroll
    for (int c = 0; c < NC; c += 4)
        *(float4*)&outp[c] = make_float4(acc[c] - lg, acc[c+1] - lg, acc[c+2] - lg, acc[c+3] - lg);
}

extern "C" void kernel_launch(void* const* d_in, const int* in_sizes, int n_in,
                              void* d_out, int out_size, void* d_ws, size_t ws_size,
                              hipStream_t stream) {
    const float* x  = (const float*)d_in[0];
    const int*   ei = (const int*)d_in[1];     // [2, E]: row0=src, row1=dst
    const float* ea = (const float*)d_in[2];
    const float* W1 = (const float*)d_in[3];
    const float* b1 = (const float*)d_in[4];
    const float* W2 = (const float*)d_in[5];
    const float* b2 = (const float*)d_in[6];
    const int* src = ei;
    const int* dst = ei + NE;
    float* out = (float*)d_out;

    char* ws = (char*)d_ws;
    float* dinv       = (float*)(ws + 0);            //    400,000 B
    int*   row_start  = (int*)  (ws + 400000);       //    400,016 B (NN+1)
    int*   cursor     = (int*)  (ws + 800016);       //     25,024 B (391*16, line-padded)
    int*   bucketbase = (int*)  (ws + 825040);       //      1,568 B
    int2*  e8         = (int2*) (ws + 826608);       // 12,800,000 B
    unsigned short* h1 = (unsigned short*)(ws + 13626608);   // 12,800,000 B (bf16, dinv-prescaled)
    unsigned short* Rp = (unsigned short*)(ws + 26426608);   // 12,800,000 B (bf16, dinv-prescaled)
    float* agg2       = (float*)(ws + 39226608);     // 25,600,000 B
    short* w1t        = (short*)(ws + 64826608);     //     32,768 B -> total 64.86 MB
    int2*  bucketbuf  = (int2*)agg2;                 // 14.4 MB, aliases agg2 (dead until gatherB)

    hipMemsetAsync(cursor, 0, 391 * 16 * sizeof(int), stream);

    w1cvt_k <<<64,   256, 0, stream>>>(W1, w1t);
    phaseA_k<<<256,  256, 0, stream>>>(src, dst, ea, cursor, bucketbuf);
    scanB_k <<<1,    512, 0, stream>>>(cursor, bucketbase, row_start);
    phaseB_k<<<NBKT, 256, 0, stream>>>(bucketbase, bucketbuf, e8, row_start, dinv);

    gemm1_mfma_k <<<(NN + 63) / 64, 256, 0, stream>>>(x, w1t, dinv, h1);
    gatherA_k    <<<NN / 4, 256, 0, stream>>>(row_start, e8, dinv, h1, b1, Rp);
    gatherB_k    <<<NN / 4, 256, 0, stream>>>(row_start, e8, dinv, Rp, agg2);
    gemm3_logsm_k<<<(NN + 255) / 256, 256, 0, stream>>>(agg2, W2, b2, out);
}

// Round 7
// 378.107 us; speedup vs baseline: 1.0202x; 1.0202x over previous
//
#include <hip/hip_runtime.h>
#include <math.h>

#define NN   100000
#define NE   1600000
#define FIN  256
#define HID  64
#define NC   40
#define NBKT 391          // buckets of 256 nodes: bucket = dst >> 8
#define EPB  6250         // edges per phase-A block (256 * 6250 = NE exactly)
#define CAP  4608         // per-bucket capacity (mean 4092, sd 64 -> 8 sigma slack)
#define NT   6250         // 16-row tiles in gemm1 (6250*16 = NN exactly)

typedef __attribute__((ext_vector_type(8))) short short8;
typedef __attribute__((ext_vector_type(4))) float float4v;

static __device__ __forceinline__ short f2bf(float f) {   // RNE f32 -> bf16 bits
    unsigned u = __float_as_uint(f);
    u += 0x7FFFu + ((u >> 16) & 1u);
    return (short)(u >> 16);
}
static __device__ __forceinline__ float bf2f(unsigned short b) {
    return __uint_as_float((unsigned)b << 16);
}

// ---------- W1 -> bf16, transposed to [n][k] ----------
__global__ __launch_bounds__(256) void w1cvt_k(const float* __restrict__ W1,
                                               short* __restrict__ w1t) {
    int t = blockIdx.x * 256 + threadIdx.x;   // 16384
    int k = t >> 6, n = t & 63;
    w1t[n * FIN + k] = f2bf(W1[k * HID + n]);
}

// ---------- phase A: partition edges into 391 coarse buckets ----------
__global__ __launch_bounds__(256) void phaseA_k(const int* __restrict__ src,
                                                const int* __restrict__ dst,
                                                const float* __restrict__ w,
                                                int* __restrict__ cursor,      // [NBKT*16]
                                                int2* __restrict__ bucketbuf) {
    __shared__ int  hist[NBKT];
    __shared__ int  sc[512];
    __shared__ int  loc_base[NBKT];
    __shared__ int  loc_cur[NBKT];
    __shared__ int  gb[NBKT];
    __shared__ int2 buf[EPB];          // 50 KB
    const int t  = threadIdx.x;
    const int e0 = blockIdx.x * EPB;

    for (int i = t; i < NBKT; i += 256) hist[i] = 0;
    __syncthreads();
    for (int i = t; i < EPB; i += 256) atomicAdd(&hist[dst[e0 + i] >> 8], 1);
    __syncthreads();
    sc[t]       = (t       < NBKT) ? hist[t]       : 0;
    sc[t + 256] = (t + 256 < NBKT) ? hist[t + 256] : 0;
    __syncthreads();
    for (int off = 1; off < 512; off <<= 1) {
        int a0 = (t >= off) ? sc[t - off] : 0;
        int a1 = sc[t + 256 - off];
        __syncthreads();
        sc[t] += a0; sc[t + 256] += a1;
        __syncthreads();
    }
    for (int i = t; i < NBKT; i += 256) {
        int base = sc[i] - hist[i];
        loc_base[i] = base;
        loc_cur[i]  = base;
        gb[i] = atomicAdd(&cursor[i * 16], hist[i]);
    }
    __syncthreads();
    for (int i = t; i < EPB; i += 256) {
        int e = e0 + i;
        int d = dst[e];
        int b = d >> 8;
        int p = atomicAdd(&loc_cur[b], 1);
        buf[p] = make_int2(src[e] | ((d & 255) << 17), __float_as_int(w[e]));
    }
    __syncthreads();
    for (int b = t; b < NBKT; b += 256) {
        int lb = loc_base[b], n = hist[b];
        int2* dstp = bucketbuf + (size_t)b * CAP + gb[b];
        for (int i = 0; i < n; ++i) dstp[i] = buf[lb + i];
    }
}

// ---------- scan of bucket counts -> bucket bases ----------
__global__ __launch_bounds__(512) void scanB_k(const int* __restrict__ cursor,
                                               int* __restrict__ bucketbase,
                                               int* __restrict__ row_start) {
    __shared__ int tmp[512];
    int t = threadIdx.x;
    int v = (t < NBKT) ? cursor[t * 16] : 0;
    tmp[t] = v;
    __syncthreads();
    for (int off = 1; off < 512; off <<= 1) {
        int add = (t >= off) ? tmp[t - off] : 0;
        __syncthreads(); tmp[t] += add; __syncthreads();
    }
    if (t < NBKT) bucketbase[t] = tmp[t] - v;
    if (t == 0) { bucketbase[NBKT] = NE; row_start[NN] = NE; }
}

// ---------- phase B: per-bucket CSR build + row_start + dinv ----------
__global__ __launch_bounds__(256) void phaseB_k(const int* __restrict__ bucketbase,
                                                const int2* __restrict__ bucketbuf,
                                                int2* __restrict__ e8,
                                                int* __restrict__ row_start,
                                                float* __restrict__ dinv) {
    __shared__ int2 buf[CAP];
    __shared__ int2 buf2[CAP];
    __shared__ int  hist2[256];
    __shared__ int  tmp[256];
    __shared__ int  base2[257];
    __shared__ int  cur2[256];
    const int b = blockIdx.x, t = threadIdx.x;
    const int g0   = bucketbase[b];
    const int cntb = bucketbase[b + 1] - g0;
    const int n0   = b * 256;
    const int nnb  = (NN - n0 < 256) ? (NN - n0) : 256;

    hist2[t] = 0;
    __syncthreads();
    const int2* bb = bucketbuf + (size_t)b * CAP;
    for (int i = t; i < cntb; i += 256) {
        int2 kv = bb[i];
        buf[i] = kv;
        atomicAdd(&hist2[kv.x >> 17], 1);
    }
    __syncthreads();
    int v = hist2[t];
    tmp[t] = v;
    __syncthreads();
    for (int off = 1; off < 256; off <<= 1) {
        int add = (t >= off) ? tmp[t - off] : 0;
        __syncthreads(); tmp[t] += add; __syncthreads();
    }
    int excl = tmp[t] - v;
    base2[t] = excl;
    cur2[t]  = excl;
    if (t == 0) base2[256] = cntb;
    if (t < nnb) row_start[n0 + t] = g0 + excl;
    __syncthreads();
    for (int i = t; i < cntb; i += 256) {
        int2 kv = buf[i];
        int d = kv.x >> 17;
        int p = atomicAdd(&cur2[d], 1);
        buf2[p] = make_int2(kv.x & 0x1FFFF, kv.y);
    }
    __syncthreads();
    for (int i = t; i < cntb; i += 256) e8[g0 + i] = buf2[i];
    if (t < nnb) {
        float s = 0.f;
        int j1 = base2[t + 1];
        for (int j = base2[t]; j < j1; ++j) s += __int_as_float(buf2[j].y);
        dinv[n0 + t] = rsqrtf(1.0f + s);
    }
}

// ---------- e8scale: fold dinv[src] into edge weights (tables stay raw) ----------
__global__ __launch_bounds__(256) void e8scale_k(int2* __restrict__ e8,
                                                 const float* __restrict__ dinv) {
    int e = blockIdx.x * 256 + threadIdx.x;     // grid 6250 -> NE exactly
    int2 kv = e8[e];
    kv.y = __float_as_int(__int_as_float(kv.y) * dinv[kv.x]);
    e8[e] = kv;
}

// ---------- gemm1 staging helper: 16 x-rows -> LDS, source-XOR-swizzled ----------
static __device__ __forceinline__ void stage_tile(const float* __restrict__ x, int t,
                                                  float* buf, int lane) {
#pragma unroll
    for (int j = 0; j < 16; ++j) {
        const float* gsrc = x + (size_t)t * (16 * FIN) + j * FIN + ((lane ^ (j & 7)) << 2);
        __builtin_amdgcn_global_load_lds(
            (const __attribute__((address_space(1))) void*)gsrc,
            (__attribute__((address_space(3))) void*)(buf + j * 256), 16, 0, 0);
    }
}

// ---------- layer-1 GEMM via MFMA bf16, RAW output: h1[r] = bf16((x@W1)[r]) ----------
// Persistent waves (grid=256, 1 block/CU), per-wave double-buffered LDS staging with
// counted vmcnt(16): stage(t+1) in flight while computing t. W1 fragments live in
// 32 short8 registers (1 wave/SIMD -> VGPR-free occupancy-wise); no vmem loads in the
// loop except stages+stores, so the counted wait is exact.
__global__ __launch_bounds__(256, 1) void gemm1_mfma_k(const float* __restrict__ x,
                                                       const short* __restrict__ w1t,  // bf16 [64][256]
                                                       unsigned short* __restrict__ h1) {
    __shared__ float xs[4 * 2 * 16 * 256];   // 128 KB: 4 waves x 2 buffers x 16 rows x 1KB
    const int wave = threadIdx.x >> 6;
    const int lane = threadIdx.x & 63;
    const int m    = lane & 15;
    const int quad = lane >> 4;
    const int wid  = blockIdx.x * 4 + wave;  // 0..1023

    // preload W1 fragments: bf[nb][kc] = w1t[(nb*16+m)*256 + kc*32 + quad*8], 32 x short8
    short8 bf[4][8];
#pragma unroll
    for (int nb = 0; nb < 4; ++nb)
#pragma unroll
        for (int kc = 0; kc < 8; ++kc)
            bf[nb][kc] = *(const short8*)(w1t + (nb * 16 + m) * FIN + kc * 32 + quad * 8);

    float* buf0 = xs + (wave * 2) * (16 * 256);
    float* buf1 = buf0 + 16 * 256;
    const unsigned sw = (unsigned)(m & 7) << 4;   // read-side byte XOR key

    int t = wid, cur = 0;
    if (t < NT) stage_tile(x, t, buf0, lane);
    for (; t < NT; t += 1024) {
        int tn = t + 1024;
        float* bcur  = cur ? buf1 : buf0;
        float* bnext = cur ? buf0 : buf1;
        if (tn < NT) {
            stage_tile(x, tn, bnext, lane);
            asm volatile("s_waitcnt vmcnt(16)" ::: "memory");   // tile t fully landed
        } else {
            asm volatile("s_waitcnt vmcnt(0)" ::: "memory");
        }
        __builtin_amdgcn_sched_barrier(0);

        const char* xrow = (const char*)(bcur + m * 256);
        float4v acc0 = {0.f,0.f,0.f,0.f}, acc1 = acc0, acc2 = acc0, acc3 = acc0;
#pragma unroll
        for (int kc = 0; kc < 8; ++kc) {
            const unsigned c0 = (unsigned)(kc * 128 + quad * 32);
            float4v xa = *(const float4v*)(xrow + (c0 ^ sw));
            float4v xb = *(const float4v*)(xrow + ((c0 + 16) ^ sw));
            short8 a;
            a[0] = f2bf(xa[0]); a[1] = f2bf(xa[1]); a[2] = f2bf(xa[2]); a[3] = f2bf(xa[3]);
            a[4] = f2bf(xb[0]); a[5] = f2bf(xb[1]); a[6] = f2bf(xb[2]); a[7] = f2bf(xb[3]);
            acc0 = __builtin_amdgcn_mfma_f32_16x16x32_bf16(a, bf[0][kc], acc0, 0, 0, 0);
            acc1 = __builtin_amdgcn_mfma_f32_16x16x32_bf16(a, bf[1][kc], acc1, 0, 0, 0);
            acc2 = __builtin_amdgcn_mfma_f32_16x16x32_bf16(a, bf[2][kc], acc2, 0, 0, 0);
            acc3 = __builtin_amdgcn_mfma_f32_16x16x32_bf16(a, bf[3][kc], acc3, 0, 0, 0);
        }
        // C/D layout: col = lane&15, row = quad*4 + reg;  NT*16 == NN, no bounds needed
#pragma unroll
        for (int r = 0; r < 4; ++r) {
            int rr = t * 16 + quad * 4 + r;
            unsigned short* hp = h1 + (size_t)rr * HID + m;
            hp[0]  = (unsigned short)f2bf(acc0[r]);
            hp[16] = (unsigned short)f2bf(acc1[r]);
            hp[32] = (unsigned short)f2bf(acc2[r]);
            hp[48] = (unsigned short)f2bf(acc3[r]);
        }
        cur ^= 1;
    }
}

// ---------- gatherA: 8 edge-slots x 8 feat-lanes (uint4 = 8 bf16), 2-deep unroll ----------
// weights carry dinv[src]; tables raw. agg1 = dv*acc + dv^2*h[v]; Rp = bf16(relu(agg1+b1))
__global__ __launch_bounds__(256) void gatherA_k(const int* __restrict__ row_start,
                                                 const int2* __restrict__ e8,
                                                 const float* __restrict__ dinv,
                                                 const unsigned short* __restrict__ h,
                                                 const float* __restrict__ b1,
                                                 unsigned short* __restrict__ Rp) {
    const int v    = blockIdx.x * 4 + (threadIdx.x >> 6);
    const int lane = threadIdx.x & 63;
    const int slot = lane >> 3;          // edge slot 0..7
    const int fg   = lane & 7;           // feature group: 8 bf16 = 16 B
    const int i0 = row_start[v], i1 = row_start[v + 1];

    float acc[8] = {0.f,0.f,0.f,0.f,0.f,0.f,0.f,0.f};
    for (int i = i0; i < i1; i += 16) {   // 16 edges per iter -> 16 gathers in flight
        int iiA = i + slot, iiB = i + 8 + slot;
        bool okA = iiA < i1, okB = iiB < i1;
        int2 eA = e8[okA ? iiA : (NE - 1)];
        int2 eB = e8[okB ? iiB : (NE - 1)];
        int  sA = okA ? eA.x : 0;         // OOB slots gather hot row 0, weight 0
        int  sB = okB ? eB.x : 0;
        float wA = okA ? __int_as_float(eA.y) : 0.f;
        float wB = okB ? __int_as_float(eB.y) : 0.f;
        uint4 pA = *(const uint4*)(h + (size_t)sA * HID + fg * 8);
        uint4 pB = *(const uint4*)(h + (size_t)sB * HID + fg * 8);
        acc[0] = fmaf(__uint_as_float(pA.x << 16),         wA, acc[0]);
        acc[1] = fmaf(__uint_as_float(pA.x & 0xFFFF0000u), wA, acc[1]);
        acc[2] = fmaf(__uint_as_float(pA.y << 16),         wA, acc[2]);
        acc[3] = fmaf(__uint_as_float(pA.y & 0xFFFF0000u), wA, acc[3]);
        acc[4] = fmaf(__uint_as_float(pA.z << 16),         wA, acc[4]);
        acc[5] = fmaf(__uint_as_float(pA.z & 0xFFFF0000u), wA, acc[5]);
        acc[6] = fmaf(__uint_as_float(pA.w << 16),         wA, acc[6]);
        acc[7] = fmaf(__uint_as_float(pA.w & 0xFFFF0000u), wA, acc[7]);
        acc[0] = fmaf(__uint_as_float(pB.x << 16),         wB, acc[0]);
        acc[1] = fmaf(__uint_as_float(pB.x & 0xFFFF0000u), wB, acc[1]);
        acc[2] = fmaf(__uint_as_float(pB.y << 16),         wB, acc[2]);
        acc[3] = fmaf(__uint_as_float(pB.y & 0xFFFF0000u), wB, acc[3]);
        acc[4] = fmaf(__uint_as_float(pB.z << 16),         wB, acc[4]);
        acc[5] = fmaf(__uint_as_float(pB.z & 0xFFFF0000u), wB, acc[5]);
        acc[6] = fmaf(__uint_as_float(pB.w << 16),         wB, acc[6]);
        acc[7] = fmaf(__uint_as_float(pB.w & 0xFFFF0000u), wB, acc[7]);
    }
#pragma unroll
    for (int mk = 8; mk <= 32; mk <<= 1) {
#pragma unroll
        for (int q = 0; q < 8; ++q) acc[q] += __shfl_xor(acc[q], mk);
    }

    const float dv  = dinv[v];
    const float dv2 = dv * dv;
    uint4 ps = *(const uint4*)(h + (size_t)v * HID + fg * 8);   // self-loop row (raw)
    float4 bA = *(const float4*)(b1 + fg * 8);
    float4 bB = *(const float4*)(b1 + fg * 8 + 4);
    float r0 = fmaxf(dv * acc[0] + dv2 * __uint_as_float(ps.x << 16)         + bA.x, 0.f);
    float r1 = fmaxf(dv * acc[1] + dv2 * __uint_as_float(ps.x & 0xFFFF0000u) + bA.y, 0.f);
    float r2 = fmaxf(dv * acc[2] + dv2 * __uint_as_float(ps.y << 16)         + bA.z, 0.f);
    float r3 = fmaxf(dv * acc[3] + dv2 * __uint_as_float(ps.y & 0xFFFF0000u) + bA.w, 0.f);
    float r4 = fmaxf(dv * acc[4] + dv2 * __uint_as_float(ps.z << 16)         + bB.x, 0.f);
    float r5 = fmaxf(dv * acc[5] + dv2 * __uint_as_float(ps.z & 0xFFFF0000u) + bB.y, 0.f);
    float r6 = fmaxf(dv * acc[6] + dv2 * __uint_as_float(ps.w << 16)         + bB.z, 0.f);
    float r7 = fmaxf(dv * acc[7] + dv2 * __uint_as_float(ps.w & 0xFFFF0000u) + bB.w, 0.f);
    if (slot == 0) {
        uint4 pk;
        pk.x = (unsigned)(unsigned short)f2bf(r0) | ((unsigned)(unsigned short)f2bf(r1) << 16);
        pk.y = (unsigned)(unsigned short)f2bf(r2) | ((unsigned)(unsigned short)f2bf(r3) << 16);
        pk.z = (unsigned)(unsigned short)f2bf(r4) | ((unsigned)(unsigned short)f2bf(r5) << 16);
        pk.w = (unsigned)(unsigned short)f2bf(r6) | ((unsigned)(unsigned short)f2bf(r7) << 16);
        *(uint4*)(Rp + (size_t)v * HID + fg * 8) = pk;          // raw (weights carry dinv)
    }
}

// ---------- gatherB: same structure; agg2 = dv*acc + dv^2*Rp[v] ----------
__global__ __launch_bounds__(256) void gatherB_k(const int* __restrict__ row_start,
                                                 const int2* __restrict__ e8,
                                                 const float* __restrict__ dinv,
                                                 const unsigned short* __restrict__ Rp,
                                                 float* __restrict__ agg2) {
    const int v    = blockIdx.x * 4 + (threadIdx.x >> 6);
    const int lane = threadIdx.x & 63;
    const int slot = lane >> 3;
    const int fg   = lane & 7;
    const int i0 = row_start[v], i1 = row_start[v + 1];

    float acc[8] = {0.f,0.f,0.f,0.f,0.f,0.f,0.f,0.f};
    for (int i = i0; i < i1; i += 16) {
        int iiA = i + slot, iiB = i + 8 + slot;
        bool okA = iiA < i1, okB = iiB < i1;
        int2 eA = e8[okA ? iiA : (NE - 1)];
        int2 eB = e8[okB ? iiB : (NE - 1)];
        int  sA = okA ? eA.x : 0;
        int  sB = okB ? eB.x : 0;
        float wA = okA ? __int_as_float(eA.y) : 0.f;
        float wB = okB ? __int_as_float(eB.y) : 0.f;
        uint4 pA = *(const uint4*)(Rp + (size_t)sA * HID + fg * 8);
        uint4 pB = *(const uint4*)(Rp + (size_t)sB * HID + fg * 8);
        acc[0] = fmaf(__uint_as_float(pA.x << 16),         wA, acc[0]);
        acc[1] = fmaf(__uint_as_float(pA.x & 0xFFFF0000u), wA, acc[1]);
        acc[2] = fmaf(__uint_as_float(pA.y << 16),         wA, acc[2]);
        acc[3] = fmaf(__uint_as_float(pA.y & 0xFFFF0000u), wA, acc[3]);
        acc[4] = fmaf(__uint_as_float(pA.z << 16),         wA, acc[4]);
        acc[5] = fmaf(__uint_as_float(pA.z & 0xFFFF0000u), wA, acc[5]);
        acc[6] = fmaf(__uint_as_float(pA.w << 16),         wA, acc[6]);
        acc[7] = fmaf(__uint_as_float(pA.w & 0xFFFF0000u), wA, acc[7]);
        acc[0] = fmaf(__uint_as_float(pB.x << 16),         wB, acc[0]);
        acc[1] = fmaf(__uint_as_float(pB.x & 0xFFFF0000u), wB, acc[1]);
        acc[2] = fmaf(__uint_as_float(pB.y << 16),         wB, acc[2]);
        acc[3] = fmaf(__uint_as_float(pB.y & 0xFFFF0000u), wB, acc[3]);
        acc[4] = fmaf(__uint_as_float(pB.z << 16),         wB, acc[4]);
        acc[5] = fmaf(__uint_as_float(pB.z & 0xFFFF0000u), wB, acc[5]);
        acc[6] = fmaf(__uint_as_float(pB.w << 16),         wB, acc[6]);
        acc[7] = fmaf(__uint_as_float(pB.w & 0xFFFF0000u), wB, acc[7]);
    }
#pragma unroll
    for (int mk = 8; mk <= 32; mk <<= 1) {
#pragma unroll
        for (int q = 0; q < 8; ++q) acc[q] += __shfl_xor(acc[q], mk);
    }

    const float dv  = dinv[v];
    const float dv2 = dv * dv;
    uint4 ps = *(const uint4*)(Rp + (size_t)v * HID + fg * 8);
    if (slot == 0) {
        float4 oA, oB;
        oA.x = dv * acc[0] + dv2 * __uint_as_float(ps.x << 16);
        oA.y = dv * acc[1] + dv2 * __uint_as_float(ps.x & 0xFFFF0000u);
        oA.z = dv * acc[2] + dv2 * __uint_as_float(ps.y << 16);
        oA.w = dv * acc[3] + dv2 * __uint_as_float(ps.y & 0xFFFF0000u);
        oB.x = dv * acc[4] + dv2 * __uint_as_float(ps.z << 16);
        oB.y = dv * acc[5] + dv2 * __uint_as_float(ps.z & 0xFFFF0000u);
        oB.z = dv * acc[6] + dv2 * __uint_as_float(ps.w << 16);
        oB.w = dv * acc[7] + dv2 * __uint_as_float(ps.w & 0xFFFF0000u);
        *(float4*)(agg2 + (size_t)v * HID + fg * 8)     = oA;
        *(float4*)(agg2 + (size_t)v * HID + fg * 8 + 4) = oB;
    }
}

// ---------- gemm3 + log_softmax: out = logsm(agg2 @ W2 + b2), thread per node ----------
__global__ __launch_bounds__(256) void gemm3_logsm_k(const float* __restrict__ agg2,
                                                     const float* __restrict__ W2,
                                                     const float* __restrict__ b2,
                                                     float* __restrict__ out) {
    __shared__ float w2s[HID * NC];
    __shared__ float b2s[NC];
    for (int i = threadIdx.x; i < HID * NC; i += 256) w2s[i] = W2[i];
    if (threadIdx.x < NC) b2s[threadIdx.x] = b2[threadIdx.x];
    __syncthreads();

    const int r = blockIdx.x * 256 + threadIdx.x;
    if (r >= NN) return;
    float acc[NC];
#pragma unroll
    for (int c = 0; c < NC; ++c) acc[c] = b2s[c];

    const float4* row4 = (const float4*)(agg2 + (size_t)r * HID);
    for (int kk = 0; kk < HID; kk += 4) {
        float4 v = row4[kk >> 2];
#pragma unroll
        for (int c = 0; c < NC; ++c) {
            acc[c] = fmaf(v.x, w2s[(kk + 0) * NC + c], acc[c]);
            acc[c] = fmaf(v.y, w2s[(kk + 1) * NC + c], acc[c]);
            acc[c] = fmaf(v.z, w2s[(kk + 2) * NC + c], acc[c]);
            acc[c] = fmaf(v.w, w2s[(kk + 3) * NC + c], acc[c]);
        }
    }
    float m = acc[0];
#pragma unroll
    for (int c = 1; c < NC; ++c) m = fmaxf(m, acc[c]);
    float s = 0.f;
#pragma unroll
    for (int c = 0; c < NC; ++c) s += __expf(acc[c] - m);
    float lg = m + __logf(s);
    float* outp = out + (size_t)r * NC;
#pragma unroll
    for (int c = 0; c < NC; c += 4)
        *(float4*)&outp[c] = make_float4(acc[c] - lg, acc[c+1] - lg, acc[c+2] - lg, acc[c+3] - lg);
}

extern "C" void kernel_launch(void* const* d_in, const int* in_sizes, int n_in,
                              void* d_out, int out_size, void* d_ws, size_t ws_size,
                              hipStream_t stream) {
    const float* x  = (const float*)d_in[0];
    const int*   ei = (const int*)d_in[1];     // [2, E]: row0=src, row1=dst
    const float* ea = (const float*)d_in[2];
    const float* W1 = (const float*)d_in[3];
    const float* b1 = (const float*)d_in[4];
    const float* W2 = (const float*)d_in[5];
    const float* b2 = (const float*)d_in[6];
    const int* src = ei;
    const int* dst = ei + NE;
    float* out = (float*)d_out;

    char* ws = (char*)d_ws;
    float* dinv       = (float*)(ws + 0);            //    400,000 B
    int*   row_start  = (int*)  (ws + 400000);       //    400,016 B (NN+1)
    int*   cursor     = (int*)  (ws + 800016);       //     25,024 B (391*16, line-padded)
    int*   bucketbase = (int*)  (ws + 825040);       //      1,568 B
    int2*  e8         = (int2*) (ws + 826608);       // 12,800,000 B
    unsigned short* h1 = (unsigned short*)(ws + 13626608);   // 12,800,000 B (bf16, RAW)
    unsigned short* Rp = (unsigned short*)(ws + 26426608);   // 12,800,000 B (bf16, RAW)
    float* agg2       = (float*)(ws + 39226608);     // 25,600,000 B
    short* w1t        = (short*)(ws + 64826608);     //     32,768 B -> total 64.86 MB
    int2*  bucketbuf  = (int2*)agg2;                 // 14.4 MB, aliases agg2 (dead until gatherB)

    hipMemsetAsync(cursor, 0, 391 * 16 * sizeof(int), stream);

    w1cvt_k <<<64,   256, 0, stream>>>(W1, w1t);
    phaseA_k<<<256,  256, 0, stream>>>(src, dst, ea, cursor, bucketbuf);
    scanB_k <<<1,    512, 0, stream>>>(cursor, bucketbase, row_start);
    phaseB_k<<<NBKT, 256, 0, stream>>>(bucketbase, bucketbuf, e8, row_start, dinv);
    e8scale_k<<<NE / 256, 256, 0, stream>>>(e8, dinv);

    gemm1_mfma_k <<<256,  256, 0, stream>>>(x, w1t, h1);
    gatherA_k    <<<NN / 4, 256, 0, stream>>>(row_start, e8, dinv, h1, b1, Rp);
    gatherB_k    <<<NN / 4, 256, 0, stream>>>(row_start, e8, dinv, Rp, agg2);
    gemm3_logsm_k<<<(NN + 255) / 256, 256, 0, stream>>>(agg2, W2, b2, out);
}